// Round 3
// baseline (300.950 us; speedup 1.0000x reference)
//
#include <hip/hip_runtime.h>

typedef short s16x8 __attribute__((ext_vector_type(8)));
typedef float f32x4 __attribute__((ext_vector_type(4)));

#define CBIAS 256.0f  // > max ||x||^2 (chi2_128 tail); makes all packed d positive

__device__ inline unsigned short bf16_rn(float f) {
  unsigned int u = __float_as_uint(f);
  return (unsigned short)((u + 0x7FFFu + ((u >> 16) & 1u)) >> 16);
}
__device__ inline float bf16f(unsigned short h) {
  return __uint_as_float(((unsigned int)h) << 16);
}
__device__ inline unsigned int umn(unsigned int a, unsigned int b) { return a < b ? a : b; }
__device__ inline unsigned int umx(unsigned int a, unsigned int b) { return a > b ? a : b; }

// ---------------------------------------------------------------------------
// Kernel 1: codebook -> tiled XOR-swizzled hi/lo bf16 image + biased norms.
// Tile = 64 codes. Row r: chunk c (8 dims) stored at chunk c ^ (r & 15).
// cbn[k] = CBIAS + ||e_k||^2.
// ---------------------------------------------------------------------------
__global__ __launch_bounds__(256) void vq_convert_cb(const float* __restrict__ cb,
                                                     unsigned short* __restrict__ cbimg,
                                                     float* __restrict__ cbn) {
  int k = blockIdx.x * 256 + threadIdx.x;  // 0..1023
  int tile = k >> 6, r = k & 63, sm = r & 15;
  const float* row = cb + (size_t)k * 128;
  float nrm = 0.f;
#pragma unroll
  for (int c = 0; c < 16; ++c) {
    float4 a = *(const float4*)(row + c * 8);
    float4 b = *(const float4*)(row + c * 8 + 4);
    float v[8] = {a.x, a.y, a.z, a.w, b.x, b.y, b.z, b.w};
    unsigned int hw[4], lw[4];
#pragma unroll
    for (int i = 0; i < 4; ++i) {
      unsigned short h0 = bf16_rn(v[2 * i]), h1 = bf16_rn(v[2 * i + 1]);
      float r0 = v[2 * i] - bf16f(h0), r1 = v[2 * i + 1] - bf16f(h1);
      unsigned short l0 = bf16_rn(r0), l1 = bf16_rn(r1);
      hw[i] = (unsigned)h0 | ((unsigned)h1 << 16);
      lw[i] = (unsigned)l0 | ((unsigned)l1 << 16);
      nrm += v[2 * i] * v[2 * i] + v[2 * i + 1] * v[2 * i + 1];
    }
    int cs = c ^ sm;
    unsigned short* dh = cbimg + (size_t)tile * 16384 + r * 128 + cs * 8;
    *(uint4*)dh = make_uint4(hw[0], hw[1], hw[2], hw[3]);
    *(uint4*)(dh + 8192) = make_uint4(lw[0], lw[1], lw[2], lw[3]);
  }
  cbn[k] = CBIAS + nrm;
}

// ---------------------------------------------------------------------------
// Kernel 2: main distance+argmin. Grid 512 = 256 token-groups x 2 K-halves.
// 4 waves/block, wave owns 64 tokens (A hi/lo frags in regs, split in-kernel).
// Streams its half's 8 codebook tiles through dbuf LDS; 3-pass split-bf16
// MFMA; packed-uint top-3 per (r,g); writes 3 candidate ids per token-half.
// ---------------------------------------------------------------------------
__global__ __launch_bounds__(256, 2) void vq_main(
    const float* __restrict__ xg, const unsigned short* __restrict__ cbimg,
    const float* __restrict__ cbn, unsigned int* __restrict__ cand) {
  __shared__ __attribute__((aligned(16))) unsigned short sB[2][16384];  // 64 KB
  const int tid = threadIdx.x;
  const int wave = tid >> 6, lane = tid & 63;
  const int i0 = lane & 15, q = lane >> 4;
  const int half = blockIdx.x & 1;
  const int grp = blockIdx.x >> 1;
  const int tok0 = grp * 256 + wave * 64;
  const int tbase = half * 8;

  // ---- load own tokens, split fp32 -> bf16 hi + bf16 lo in-register ----
  s16x8 ahi[4][4], alo[4][4];
#pragma unroll
  for (int r = 0; r < 4; ++r)
#pragma unroll
    for (int kf = 0; kf < 4; ++kf) {
      const float* p = xg + (size_t)(tok0 + r * 16 + i0) * 128 + kf * 32 + q * 8;
      float4 a = *(const float4*)p, b = *(const float4*)(p + 4);
      float v[8] = {a.x, a.y, a.z, a.w, b.x, b.y, b.z, b.w};
      s16x8 h, l;
#pragma unroll
      for (int j = 0; j < 8; ++j) {
        unsigned short hh = bf16_rn(v[j]);
        float rr = v[j] - bf16f(hh);
        h[j] = (short)hh;
        l[j] = (short)bf16_rn(rr);
      }
      ahi[r][kf] = h;
      alo[r][kf] = l;
    }

  int boff[4][4];
#pragma unroll
  for (int ks = 0; ks < 4; ++ks)
#pragma unroll
    for (int c = 0; c < 4; ++c)
      boff[ks][c] = (c * 16 + i0) * 128 + (((ks * 4 + q) ^ i0) * 8);

  // stage first tile of this half
#pragma unroll
  for (int i = 0; i < 8; ++i)
    *(uint4*)&sB[0][i * 2048 + tid * 8] =
        *(const uint4*)(cbimg + (size_t)tbase * 16384 + i * 2048 + tid * 8);

  unsigned int b1[4][4], b2[4][4], b3[4][4];
#pragma unroll
  for (int r = 0; r < 4; ++r)
#pragma unroll
    for (int g = 0; g < 4; ++g) {
      b1[r][g] = 0xFFFFFFFFu; b2[r][g] = 0xFFFFFFFFu; b3[r][g] = 0xFFFFFFFFu;
    }
  __syncthreads();

  for (int t = 0; t < 8; ++t) {
    const int cur = t & 1;
    uint4 pf[8];
    if (t < 7) {
#pragma unroll
      for (int i = 0; i < 8; ++i)
        pf[i] = *(const uint4*)(cbimg + (size_t)(tbase + t + 1) * 16384 + i * 2048 + tid * 8);
    }
    f32x4 acc[4][4];
#pragma unroll
    for (int r = 0; r < 4; ++r)
#pragma unroll
      for (int c = 0; c < 4; ++c) acc[r][c] = (f32x4){0.f, 0.f, 0.f, 0.f};

#pragma unroll
    for (int ks = 0; ks < 4; ++ks) {
      s16x8 bhi[4], blo[4];
#pragma unroll
      for (int c = 0; c < 4; ++c) {
        bhi[c] = *(const s16x8*)&sB[cur][boff[ks][c]];
        blo[c] = *(const s16x8*)&sB[cur][boff[ks][c] + 8192];
      }
#pragma unroll
      for (int r = 0; r < 4; ++r)
#pragma unroll
        for (int c = 0; c < 4; ++c) {
          acc[r][c] = __builtin_amdgcn_mfma_f32_16x16x32_bf16(ahi[r][ks], bhi[c], acc[r][c], 0, 0, 0);
          acc[r][c] = __builtin_amdgcn_mfma_f32_16x16x32_bf16(ahi[r][ks], blo[c], acc[r][c], 0, 0, 0);
          acc[r][c] = __builtin_amdgcn_mfma_f32_16x16x32_bf16(alo[r][ks], bhi[c], acc[r][c], 0, 0, 0);
        }
    }
    // ---- packed top-3 update: u = (dbits & ~31) | (t*4+c); positive d sorts as uint
#pragma unroll
    for (int c = 0; c < 4; ++c) {
      float cnv = cbn[(tbase + t) * 64 + c * 16 + i0];
      unsigned int sid = (unsigned)(t * 4 + c);
#pragma unroll
      for (int r = 0; r < 4; ++r)
#pragma unroll
        for (int g = 0; g < 4; ++g) {
          float dd = fmaf(-2.f, acc[r][c][g], cnv);
          unsigned int u = (__float_as_uint(dd) & 0xFFFFFFE0u) | sid;
          unsigned int m1 = umx(b1[r][g], u);
          b1[r][g] = umn(b1[r][g], u);
          unsigned int m2 = umx(b2[r][g], m1);
          b2[r][g] = umn(b2[r][g], m1);
          b3[r][g] = umn(b3[r][g], m2);
        }
    }
    if (t < 7) {
#pragma unroll
      for (int i = 0; i < 8; ++i) *(uint4*)&sB[1 - cur][i * 2048 + tid * 8] = pf[i];
    }
    __syncthreads();
  }

  // ---- widen id to 9-bit local k, re-sort, butterfly-merge across 16 lanes ----
  if (i0 == 0 || true) {}  // (all lanes participate)
#pragma unroll
  for (int r = 0; r < 4; ++r)
#pragma unroll
    for (int g = 0; g < 4; ++g) {
      unsigned int v1 = b1[r][g], v2 = b2[r][g], v3 = b3[r][g];
      v1 = (v1 & 0xFFFFFE00u) | (((v1 & 31u) << 4) | (unsigned)i0);
      v2 = (v2 & 0xFFFFFE00u) | (((v2 & 31u) << 4) | (unsigned)i0);
      v3 = (v3 & 0xFFFFFE00u) | (((v3 & 31u) << 4) | (unsigned)i0);
      // sort3 (repack can disorder)
      unsigned int s1 = umn(v1, v2), s2 = umx(v1, v2);
      unsigned int t2 = umn(s2, v3), t3 = umx(s2, v3);
      v1 = umn(s1, t2); v2 = umx(s1, t2); v3 = t3;
#pragma unroll
      for (int off = 1; off < 16; off <<= 1) {
        unsigned int r1 = (unsigned)__shfl_xor((int)v1, off);
        unsigned int r2 = (unsigned)__shfl_xor((int)v2, off);
        unsigned int r3 = (unsigned)__shfl_xor((int)v3, off);
        unsigned int lo1 = umn(v1, r1), hi1 = umx(v1, r1);
        unsigned int lo2 = umn(v2, r2), hi2 = umx(v2, r2);
        unsigned int n2 = umn(hi1, lo2);
        unsigned int n3 = umn(umx(hi1, lo2), umn(hi2, umn(v3, r3)));
        v1 = lo1; v2 = n2; v3 = n3;
      }
      b1[r][g] = v1; b2[r][g] = v2; b3[r][g] = v3;
    }

  if (i0 == 0) {
#pragma unroll
    for (int r = 0; r < 4; ++r)
#pragma unroll
      for (int g = 0; g < 4; ++g) {
        unsigned int k1 = (unsigned)(half << 9) + (b1[r][g] & 511u);
        unsigned int k2 = (unsigned)(half << 9) + (b2[r][g] & 511u);
        unsigned int k3 = (unsigned)(half << 9) + (b3[r][g] & 511u);
        cand[(size_t)half * 65536 + tok0 + r * 16 + q * 4 + g] =
            k1 | (k2 << 10) | (k3 << 20);
      }
  }
}

// ---------------------------------------------------------------------------
// Kernel 3: exact fp32 rescore of the 6 candidates, xq write, loss.
// 16 lanes per token, 16 tokens per 256-thr block, 4096 blocks.
// ---------------------------------------------------------------------------
__global__ __launch_bounds__(256) void vq_merge(
    const float* __restrict__ xg, const float* __restrict__ cb,
    const unsigned int* __restrict__ cand, float* __restrict__ xq,
    float* __restrict__ loss) {
  const int tid = threadIdx.x;
  const int grpi = tid >> 4, l = tid & 15;
  const int tok = blockIdx.x * 16 + grpi;
  unsigned int ca = cand[tok], cbw = cand[65536 + tok];
  int kk[6] = {(int)(ca & 1023u),  (int)((ca >> 10) & 1023u),  (int)((ca >> 20) & 1023u),
               (int)(cbw & 1023u), (int)((cbw >> 10) & 1023u), (int)((cbw >> 20) & 1023u)};
  const float* xp = xg + (size_t)tok * 128 + l * 8;
  float4 xa = *(const float4*)xp, xb = *(const float4*)(xp + 4);
  float xv[8] = {xa.x, xa.y, xa.z, xa.w, xb.x, xb.y, xb.z, xb.w};

  float er[6][8], d[6];
#pragma unroll
  for (int i = 0; i < 6; ++i) {
    const float* ep = cb + (size_t)kk[i] * 128 + l * 8;
    float4 ea = *(const float4*)ep, eb = *(const float4*)(ep + 4);
    er[i][0] = ea.x; er[i][1] = ea.y; er[i][2] = ea.z; er[i][3] = ea.w;
    er[i][4] = eb.x; er[i][5] = eb.y; er[i][6] = eb.z; er[i][7] = eb.w;
    float s = 0.f;
#pragma unroll
    for (int j = 0; j < 8; ++j) {
      float df = xv[j] - er[i][j];
      s = fmaf(df, df, s);
    }
    d[i] = s;
  }
#pragma unroll
  for (int i = 0; i < 6; ++i) {
#pragma unroll
    for (int off = 1; off < 16; off <<= 1) d[i] += __shfl_xor(d[i], off);
  }
  // lexicographic (d, k) first-min — matches jnp.argmin tie semantics
  float bd = d[0]; int bk = kk[0], bi = 0;
#pragma unroll
  for (int i = 1; i < 6; ++i) {
    bool t = (d[i] < bd) || (d[i] == bd && kk[i] < bk);
    bd = t ? d[i] : bd; bk = t ? kk[i] : bk; bi = t ? i : bi;
  }
  float w[8];
#pragma unroll
  for (int j = 0; j < 8; ++j) {
    float v = er[0][j];
    v = bi == 1 ? er[1][j] : v;
    v = bi == 2 ? er[2][j] : v;
    v = bi == 3 ? er[3][j] : v;
    v = bi == 4 ? er[4][j] : v;
    v = bi == 5 ? er[5][j] : v;
    w[j] = v;
  }
  float* op = xq + (size_t)tok * 128 + l * 8;
  *(float4*)op = make_float4(w[0], w[1], w[2], w[3]);
  *(float4*)(op + 4) = make_float4(w[4], w[5], w[6], w[7]);

  float lacc = (l == 0) ? bd : 0.f;
#pragma unroll
  for (int off = 1; off < 64; off <<= 1) lacc += __shfl_xor(lacc, off);
  if ((tid & 63) == 0) atomicAdd(&loss[blockIdx.x >> 3], lacc * (1.25f / 16384.f));
}

// ---------------------------------------------------------------------------
extern "C" void kernel_launch(void* const* d_in, const int* in_sizes, int n_in,
                              void* d_out, int out_size, void* d_ws, size_t ws_size,
                              hipStream_t stream) {
  const float* x = (const float*)d_in[0];   // [8,64,128,128] fp32
  const float* cb = (const float*)d_in[1];  // [1024,128] fp32
  float* out = (float*)d_out;
  float* xq = out;
  float* loss = out + (size_t)8 * 64 * 128 * 128;  // 512 floats

  // ws: cbimg 512 KB | cbn 4 KB | cand 512 KB
  unsigned short* cbimg = (unsigned short*)d_ws;
  float* cbn = (float*)(cbimg + (size_t)1024 * 128 * 2);
  unsigned int* cand = (unsigned int*)(cbn + 1024);

  hipMemsetAsync(loss, 0, 512 * sizeof(float), stream);
  vq_convert_cb<<<4, 256, 0, stream>>>(cb, cbimg, cbn);
  vq_main<<<512, 256, 0, stream>>>(x, cbimg, cbn, cand);
  vq_merge<<<4096, 256, 0, stream>>>(x, cb, cand, xq, loss);
}

// Round 4
// 194.035 us; speedup vs baseline: 1.5510x; 1.5510x over previous
//
#include <hip/hip_runtime.h>

typedef short s16x8 __attribute__((ext_vector_type(8)));
typedef float f32x4 __attribute__((ext_vector_type(4)));

__device__ inline unsigned short bf16_rn(float f) {
  unsigned int u = __float_as_uint(f);
  return (unsigned short)((u + 0x7FFFu + ((u >> 16) & 1u)) >> 16);
}
__device__ inline float bf16f(unsigned short h) {
  return __uint_as_float(((unsigned int)h) << 16);
}

// ---------------------------------------------------------------------------
// Kernel 1: codebook -> tiled XOR-swizzled hi/lo bf16 image + exact norms.
// Tile = 64 codes: [hi 64x128 ushort | lo 64x128 ushort]. Row r stores
// 8-dim chunk c at chunk slot c ^ (r & 15)  (conflict-free LDS reads later).
// ---------------------------------------------------------------------------
__global__ __launch_bounds__(256) void vq_convert_cb(const float* __restrict__ cb,
                                                     unsigned short* __restrict__ cbimg,
                                                     float* __restrict__ cbn) {
  int k = blockIdx.x * 256 + threadIdx.x;  // 0..1023
  int tile = k >> 6, r = k & 63, sm = r & 15;
  const float* row = cb + (size_t)k * 128;
  float nrm = 0.f;
#pragma unroll
  for (int c = 0; c < 16; ++c) {
    float4 a = *(const float4*)(row + c * 8);
    float4 b = *(const float4*)(row + c * 8 + 4);
    float v[8] = {a.x, a.y, a.z, a.w, b.x, b.y, b.z, b.w};
    unsigned int hw[4], lw[4];
#pragma unroll
    for (int i = 0; i < 4; ++i) {
      unsigned short h0 = bf16_rn(v[2 * i]), h1 = bf16_rn(v[2 * i + 1]);
      float r0 = v[2 * i] - bf16f(h0), r1 = v[2 * i + 1] - bf16f(h1);
      unsigned short l0 = bf16_rn(r0), l1 = bf16_rn(r1);
      hw[i] = (unsigned)h0 | ((unsigned)h1 << 16);
      lw[i] = (unsigned)l0 | ((unsigned)l1 << 16);
      nrm += v[2 * i] * v[2 * i] + v[2 * i + 1] * v[2 * i + 1];
    }
    int cs = c ^ sm;
    unsigned short* dh = cbimg + (size_t)tile * 16384 + r * 128 + cs * 8;
    *(uint4*)dh = make_uint4(hw[0], hw[1], hw[2], hw[3]);
    *(uint4*)(dh + 8192) = make_uint4(lw[0], lw[1], lw[2], lw[3]);
  }
  cbn[k] = nrm;
}

// ---------------------------------------------------------------------------
// Kernel 2: fused main. 512 blocks x 256 thr (4 waves), 2 blocks/CU.
// Wave owns 32 tokens (A hi/lo frags in regs, r=2 row-frags). All 16
// codebook tiles stream through dbuf LDS; 3-pass split-bf16 MFMA;
// EXACT-float top-2 (d,k) tracking; fused exact-fp32 rescore epilogue
// (re-reads x fp32) writes xq + loss.
// ---------------------------------------------------------------------------
__global__ __launch_bounds__(256, 2) void vq_main(
    const float* __restrict__ xg, const float* __restrict__ cb,
    const unsigned short* __restrict__ cbimg, const float* __restrict__ cbn,
    float* __restrict__ xq, float* __restrict__ loss) {
  __shared__ __attribute__((aligned(16))) unsigned short sB[2][16384];  // 64 KB
  __shared__ int sKK[128];
  const int tid = threadIdx.x;
  const int wave = tid >> 6, lane = tid & 63;
  const int i0 = lane & 15, q = lane >> 4;
  const int tok0 = blockIdx.x * 128 + wave * 32;

  // ---- load own 32 tokens, split fp32 -> bf16 hi + bf16 lo in-register ----
  s16x8 ahi[2][4], alo[2][4];
#pragma unroll
  for (int r = 0; r < 2; ++r)
#pragma unroll
    for (int kf = 0; kf < 4; ++kf) {
      const float* p = xg + (size_t)(tok0 + r * 16 + i0) * 128 + kf * 32 + q * 8;
      float4 a = *(const float4*)p, b = *(const float4*)(p + 4);
      float v[8] = {a.x, a.y, a.z, a.w, b.x, b.y, b.z, b.w};
      s16x8 h, l;
#pragma unroll
      for (int j = 0; j < 8; ++j) {
        unsigned short hh = bf16_rn(v[j]);
        float rr = v[j] - bf16f(hh);
        h[j] = (short)hh;
        l[j] = (short)bf16_rn(rr);
      }
      ahi[r][kf] = h;
      alo[r][kf] = l;
    }

  int boff[4][4];  // LDS ushort offsets for B-frag reads (XOR de-swizzle)
#pragma unroll
  for (int ks = 0; ks < 4; ++ks)
#pragma unroll
    for (int c = 0; c < 4; ++c)
      boff[ks][c] = (c * 16 + i0) * 128 + (((ks * 4 + q) ^ i0) * 8);

  // stage tile 0
#pragma unroll
  for (int i = 0; i < 8; ++i)
    *(uint4*)&sB[0][i * 2048 + tid * 8] = *(const uint4*)(cbimg + i * 2048 + tid * 8);

  float d1[2][4], d2[2][4];
  int k1[2][4], k2[2][4];
#pragma unroll
  for (int r = 0; r < 2; ++r)
#pragma unroll
    for (int g = 0; g < 4; ++g) {
      d1[r][g] = 3.4e38f; d2[r][g] = 3.4e38f; k1[r][g] = 0; k2[r][g] = 0;
    }
  __syncthreads();

  for (int t = 0; t < 16; ++t) {
    const int cur = t & 1;
    uint4 pf[8];
    if (t < 15) {
#pragma unroll
      for (int i = 0; i < 8; ++i)
        pf[i] = *(const uint4*)(cbimg + (size_t)(t + 1) * 16384 + i * 2048 + tid * 8);
    }
    f32x4 acc[2][4];
#pragma unroll
    for (int r = 0; r < 2; ++r)
#pragma unroll
      for (int c = 0; c < 4; ++c) acc[r][c] = (f32x4){0.f, 0.f, 0.f, 0.f};

#pragma unroll
    for (int ks = 0; ks < 4; ++ks) {
      s16x8 bhi[4], blo[4];
#pragma unroll
      for (int c = 0; c < 4; ++c) {
        bhi[c] = *(const s16x8*)&sB[cur][boff[ks][c]];
        blo[c] = *(const s16x8*)&sB[cur][boff[ks][c] + 8192];
      }
#pragma unroll
      for (int r = 0; r < 2; ++r)
#pragma unroll
        for (int c = 0; c < 4; ++c) {
          acc[r][c] = __builtin_amdgcn_mfma_f32_16x16x32_bf16(ahi[r][ks], bhi[c], acc[r][c], 0, 0, 0);
          acc[r][c] = __builtin_amdgcn_mfma_f32_16x16x32_bf16(ahi[r][ks], blo[c], acc[r][c], 0, 0, 0);
          acc[r][c] = __builtin_amdgcn_mfma_f32_16x16x32_bf16(alo[r][ks], bhi[c], acc[r][c], 0, 0, 0);
        }
    }
    // ---- EXACT top-2 update; k scanned ascending => strict < keeps first-min
#pragma unroll
    for (int c = 0; c < 4; ++c) {
      int kc = t * 64 + c * 16 + i0;
      float cn = cbn[kc];
#pragma unroll
      for (int r = 0; r < 2; ++r)
#pragma unroll
        for (int g = 0; g < 4; ++g) {
          float dd = fmaf(-2.f, acc[r][c][g], cn);
          bool w = dd < d1[r][g];
          float ld = w ? d1[r][g] : dd;
          int lk = w ? k1[r][g] : kc;
          d1[r][g] = w ? dd : d1[r][g];
          k1[r][g] = w ? kc : k1[r][g];
          bool w2 = ld < d2[r][g];
          d2[r][g] = w2 ? ld : d2[r][g];
          k2[r][g] = w2 ? lk : k2[r][g];
        }
    }
    if (t < 15) {
#pragma unroll
      for (int i = 0; i < 8; ++i) *(uint4*)&sB[1 - cur][i * 2048 + tid * 8] = pf[i];
    }
    __syncthreads();
  }

  // ---- butterfly merge of sorted pairs across the 16 i0-lanes (lex d,k) ----
#pragma unroll
  for (int off = 1; off < 16; off <<= 1) {
#pragma unroll
    for (int r = 0; r < 2; ++r)
#pragma unroll
      for (int g = 0; g < 4; ++g) {
        float od1 = __shfl_xor(d1[r][g], off);
        int ok1 = __shfl_xor(k1[r][g], off);
        float od2 = __shfl_xor(d2[r][g], off);
        int ok2 = __shfl_xor(k2[r][g], off);
        bool t1 = (od1 < d1[r][g]) || (od1 == d1[r][g] && ok1 < k1[r][g]);
        float w1d = t1 ? od1 : d1[r][g];
        int w1k = t1 ? ok1 : k1[r][g];
        float l1d = t1 ? d1[r][g] : od1;   // loser of the firsts
        int l1k = t1 ? k1[r][g] : ok1;
        float c2d = t1 ? od2 : d2[r][g];   // winner's own second
        int c2k = t1 ? ok2 : k2[r][g];
        bool t2 = (l1d < c2d) || (l1d == c2d && l1k < c2k);
        d1[r][g] = w1d; k1[r][g] = w1k;
        d2[r][g] = t2 ? l1d : c2d;
        k2[r][g] = t2 ? l1k : c2k;
      }
  }

  if (i0 == 0) {
#pragma unroll
    for (int r = 0; r < 2; ++r)
#pragma unroll
      for (int g = 0; g < 4; ++g)
        sKK[wave * 32 + r * 16 + q * 4 + g] = k1[r][g] | (k2[r][g] << 10);
  }
  __syncthreads();

  // ---- fused epilogue: exact fp32 rescore of {k1,k2}, xq write, loss ----
  float lacc = 0.f;
#pragma unroll
  for (int r = 0; r < 2; ++r) {
    int kk = sKK[wave * 32 + r * 16 + i0];
    int ka = kk & 1023, kb = (kk >> 10) & 1023;
    size_t token = (size_t)tok0 + r * 16 + i0;
    float e1v[32], e2v[32];
    float s1 = 0.f, s2 = 0.f;
#pragma unroll
    for (int kf = 0; kf < 4; ++kf) {
      const float* xp = xg + token * 128 + kf * 32 + q * 8;
      float4 xa = *(const float4*)xp, xb = *(const float4*)(xp + 4);
      float xv[8] = {xa.x, xa.y, xa.z, xa.w, xb.x, xb.y, xb.z, xb.w};
      const float* p1 = cb + (size_t)ka * 128 + kf * 32 + q * 8;
      float4 u1 = *(const float4*)p1, v1 = *(const float4*)(p1 + 4);
      const float* p2 = cb + (size_t)kb * 128 + kf * 32 + q * 8;
      float4 u2 = *(const float4*)p2, v2 = *(const float4*)(p2 + 4);
      float e1[8] = {u1.x, u1.y, u1.z, u1.w, v1.x, v1.y, v1.z, v1.w};
      float e2[8] = {u2.x, u2.y, u2.z, u2.w, v2.x, v2.y, v2.z, v2.w};
#pragma unroll
      for (int j = 0; j < 8; ++j) {
        float f1 = xv[j] - e1[j];
        float f2 = xv[j] - e2[j];
        s1 = fmaf(f1, f1, s1);
        s2 = fmaf(f2, f2, s2);
        e1v[kf * 8 + j] = e1[j];
        e2v[kf * 8 + j] = e2[j];
      }
    }
    s1 += __shfl_xor(s1, 16); s1 += __shfl_xor(s1, 32);
    s2 += __shfl_xor(s2, 16); s2 += __shfl_xor(s2, 32);
    bool tk = (s2 < s1) || (s2 == s1 && kb < ka);
    float dwin = tk ? s2 : s1;
#pragma unroll
    for (int kf = 0; kf < 4; ++kf) {
      float w[8];
#pragma unroll
      for (int j = 0; j < 8; ++j) w[j] = tk ? e2v[kf * 8 + j] : e1v[kf * 8 + j];
      float* op = xq + token * 128 + kf * 32 + q * 8;
      *(float4*)op = make_float4(w[0], w[1], w[2], w[3]);
      *(float4*)(op + 4) = make_float4(w[4], w[5], w[6], w[7]);
    }
    if (q == 0) lacc += dwin;
  }
#pragma unroll
  for (int off = 1; off < 64; off <<= 1) lacc += __shfl_xor(lacc, off);
  if (lane == 0) atomicAdd(&loss[blockIdx.x], lacc * (1.25f / 16384.f));
}

// ---------------------------------------------------------------------------
extern "C" void kernel_launch(void* const* d_in, const int* in_sizes, int n_in,
                              void* d_out, int out_size, void* d_ws, size_t ws_size,
                              hipStream_t stream) {
  const float* x = (const float*)d_in[0];   // [8,64,128,128] fp32
  const float* cb = (const float*)d_in[1];  // [1024,128] fp32
  float* out = (float*)d_out;
  float* xq = out;
  float* loss = out + (size_t)8 * 64 * 128 * 128;  // 512 floats

  // ws: cbimg 512 KB | cbn 4 KB
  unsigned short* cbimg = (unsigned short*)d_ws;
  float* cbn = (float*)(cbimg + (size_t)1024 * 128 * 2);

  hipMemsetAsync(loss, 0, 512 * sizeof(float), stream);
  vq_convert_cb<<<4, 256, 0, stream>>>(cb, cbimg, cbn);
  vq_main<<<512, 256, 0, stream>>>(x, cb, cbimg, cbn, xq, loss);
}

// Round 5
// 152.833 us; speedup vs baseline: 1.9692x; 1.2696x over previous
//
#include <hip/hip_runtime.h>

typedef short s16x8 __attribute__((ext_vector_type(8)));
typedef float f32x4 __attribute__((ext_vector_type(4)));

__device__ inline unsigned short bf16_rn(float f) {
  unsigned int u = __float_as_uint(f);
  return (unsigned short)((u + 0x7FFFu + ((u >> 16) & 1u)) >> 16);
}
__device__ inline float bf16f(unsigned short h) {
  return __uint_as_float(((unsigned int)h) << 16);
}

// async global->LDS DMA, 16 B per lane; LDS dest = wave-uniform base + lane*16
typedef __attribute__((address_space(3))) unsigned int lds_u32_t;
typedef __attribute__((address_space(1))) const unsigned int g_u32_t;
__device__ __forceinline__ void gload_lds16(const void* g, void* l) {
  __builtin_amdgcn_global_load_lds((g_u32_t*)g, (lds_u32_t*)l, 16, 0, 0);
}

// ---------------------------------------------------------------------------
// Kernel 1: codebook -> tiled XOR-swizzled hi/lo bf16 image + exact norms.
// Tile = 64 codes: [hi 64x128 ushort | lo 64x128 ushort]. Row r stores
// 8-dim chunk c at chunk slot c ^ (r & 15)  (conflict-free LDS reads later).
// ---------------------------------------------------------------------------
__global__ __launch_bounds__(256) void vq_convert_cb(const float* __restrict__ cb,
                                                     unsigned short* __restrict__ cbimg,
                                                     float* __restrict__ cbn) {
  int k = blockIdx.x * 256 + threadIdx.x;  // 0..1023
  int tile = k >> 6, r = k & 63, sm = r & 15;
  const float* row = cb + (size_t)k * 128;
  float nrm = 0.f;
#pragma unroll
  for (int c = 0; c < 16; ++c) {
    float4 a = *(const float4*)(row + c * 8);
    float4 b = *(const float4*)(row + c * 8 + 4);
    float v[8] = {a.x, a.y, a.z, a.w, b.x, b.y, b.z, b.w};
    unsigned int hw[4], lw[4];
#pragma unroll
    for (int i = 0; i < 4; ++i) {
      unsigned short h0 = bf16_rn(v[2 * i]), h1 = bf16_rn(v[2 * i + 1]);
      float r0 = v[2 * i] - bf16f(h0), r1 = v[2 * i + 1] - bf16f(h1);
      unsigned short l0 = bf16_rn(r0), l1 = bf16_rn(r1);
      hw[i] = (unsigned)h0 | ((unsigned)h1 << 16);
      lw[i] = (unsigned)l0 | ((unsigned)l1 << 16);
      nrm += v[2 * i] * v[2 * i] + v[2 * i + 1] * v[2 * i + 1];
    }
    int cs = c ^ sm;
    unsigned short* dh = cbimg + (size_t)tile * 16384 + r * 128 + cs * 8;
    *(uint4*)dh = make_uint4(hw[0], hw[1], hw[2], hw[3]);
    *(uint4*)(dh + 8192) = make_uint4(lw[0], lw[1], lw[2], lw[3]);
  }
  cbn[k] = nrm;
}

// ---------------------------------------------------------------------------
// Kernel 2: fused main. 512 blocks x 256 thr (4 waves), 2 blocks/CU (LDS).
// Wave owns 32 tokens (A hi/lo frags in regs). 16 codebook tiles stream
// through dbuf LDS via async global_load_lds (no staging VGPRs); 3-pass
// split-bf16 MFMA; exact-float top-2 (d,k); two-pass exact-fp32 rescore
// epilogue (no register buffering of code rows) writes xq + loss.
// ---------------------------------------------------------------------------
__global__ __launch_bounds__(256) void vq_main(
    const float* __restrict__ xg, const float* __restrict__ cb,
    const unsigned short* __restrict__ cbimg, const float* __restrict__ cbn,
    float* __restrict__ xq, float* __restrict__ loss) {
  __shared__ __attribute__((aligned(16))) unsigned short sB[2][16384];  // 64 KB
  __shared__ float sNorm[1024];
  __shared__ int sKK[128];
  const int tid = threadIdx.x;
  const int wave = tid >> 6, lane = tid & 63;
  const int i0 = lane & 15, q = lane >> 4;
  const int tok0 = blockIdx.x * 128 + wave * 32;

  // ---- stage codebook norms into LDS (4 KB) ----
  *(float4*)&sNorm[tid * 4] = *(const float4*)(cbn + tid * 4);

  // ---- load own 32 tokens, split fp32 -> bf16 hi + bf16 lo in-register ----
  s16x8 ahi[2][4], alo[2][4];
#pragma unroll
  for (int r = 0; r < 2; ++r)
#pragma unroll
    for (int kf = 0; kf < 4; ++kf) {
      const float* p = xg + (size_t)(tok0 + r * 16 + i0) * 128 + kf * 32 + q * 8;
      float4 a = *(const float4*)p, b = *(const float4*)(p + 4);
      float v[8] = {a.x, a.y, a.z, a.w, b.x, b.y, b.z, b.w};
      s16x8 h, l;
#pragma unroll
      for (int j = 0; j < 8; ++j) {
        unsigned short hh = bf16_rn(v[j]);
        float rr = v[j] - bf16f(hh);
        h[j] = (short)hh;
        l[j] = (short)bf16_rn(rr);
      }
      ahi[r][kf] = h;
      alo[r][kf] = l;
    }

  int boff[4][4];  // LDS ushort offsets for B-frag reads (XOR de-swizzle)
#pragma unroll
  for (int ks = 0; ks < 4; ++ks)
#pragma unroll
    for (int c = 0; c < 4; ++c)
      boff[ks][c] = (c * 16 + i0) * 128 + (((ks * 4 + q) ^ i0) * 8);

  // ---- async stage tile 0 (8 x 1KB slices per wave) ----
  const char* gbase = (const char*)cbimg;
  const int so = wave * 1024 + lane * 16;  // per-lane global offset in tile
  const int su = wave * 1024;              // wave-uniform LDS offset
  {
    const char* g = gbase + so;
    char* l = (char*)&sB[0][0] + su;
#pragma unroll
    for (int i = 0; i < 8; ++i) gload_lds16(g + i * 4096, l + i * 4096);
  }

  float d1[2][4], d2[2][4];
  int k1[2][4], k2[2][4];
#pragma unroll
  for (int r = 0; r < 2; ++r)
#pragma unroll
    for (int g = 0; g < 4; ++g) {
      d1[r][g] = 3.4e38f; d2[r][g] = 3.4e38f; k1[r][g] = 0; k2[r][g] = 0;
    }
  __syncthreads();  // drains vmcnt -> tile 0 resident

  for (int t = 0; t < 16; ++t) {
    const int cur = t & 1;
    if (t < 15) {  // async prefetch of tile t+1 into the other buffer
      const char* g = gbase + (t + 1) * 32768 + so;
      char* l = (char*)&sB[1 - cur][0] + su;
#pragma unroll
      for (int i = 0; i < 8; ++i) gload_lds16(g + i * 4096, l + i * 4096);
    }
    f32x4 acc[2][4];
#pragma unroll
    for (int r = 0; r < 2; ++r)
#pragma unroll
      for (int c = 0; c < 4; ++c) acc[r][c] = (f32x4){0.f, 0.f, 0.f, 0.f};

#pragma unroll
    for (int ks = 0; ks < 4; ++ks) {
      s16x8 bhi[4], blo[4];
#pragma unroll
      for (int c = 0; c < 4; ++c) {
        bhi[c] = *(const s16x8*)&sB[cur][boff[ks][c]];
        blo[c] = *(const s16x8*)&sB[cur][boff[ks][c] + 8192];
      }
#pragma unroll
      for (int r = 0; r < 2; ++r)
#pragma unroll
        for (int c = 0; c < 4; ++c) {
          acc[r][c] = __builtin_amdgcn_mfma_f32_16x16x32_bf16(ahi[r][ks], bhi[c], acc[r][c], 0, 0, 0);
          acc[r][c] = __builtin_amdgcn_mfma_f32_16x16x32_bf16(ahi[r][ks], blo[c], acc[r][c], 0, 0, 0);
          acc[r][c] = __builtin_amdgcn_mfma_f32_16x16x32_bf16(alo[r][ks], bhi[c], acc[r][c], 0, 0, 0);
        }
    }
    // ---- exact top-2 update; k ascending => strict < keeps first-min ----
#pragma unroll
    for (int c = 0; c < 4; ++c) {
      int kc = t * 64 + c * 16 + i0;
      float cn = sNorm[kc];
#pragma unroll
      for (int r = 0; r < 2; ++r)
#pragma unroll
        for (int g = 0; g < 4; ++g) {
          float dd = fmaf(-2.f, acc[r][c][g], cn);
          bool w = dd < d1[r][g];
          float ld = w ? d1[r][g] : dd;
          int lk = w ? k1[r][g] : kc;
          d1[r][g] = w ? dd : d1[r][g];
          k1[r][g] = w ? kc : k1[r][g];
          bool w2 = ld < d2[r][g];
          d2[r][g] = w2 ? ld : d2[r][g];
          k2[r][g] = w2 ? lk : k2[r][g];
        }
    }
    __syncthreads();  // waves done reading cur; prefetch into 1-cur drained
  }

  // ---- butterfly merge of top-2 across the 16 i0-lanes (lex d,k) ----
#pragma unroll
  for (int off = 1; off < 16; off <<= 1) {
#pragma unroll
    for (int r = 0; r < 2; ++r)
#pragma unroll
      for (int g = 0; g < 4; ++g) {
        float od1 = __shfl_xor(d1[r][g], off);
        int ok1 = __shfl_xor(k1[r][g], off);
        float od2 = __shfl_xor(d2[r][g], off);
        int ok2 = __shfl_xor(k2[r][g], off);
        bool t1 = (od1 < d1[r][g]) || (od1 == d1[r][g] && ok1 < k1[r][g]);
        float w1d = t1 ? od1 : d1[r][g];
        int w1k = t1 ? ok1 : k1[r][g];
        float l1d = t1 ? d1[r][g] : od1;  // loser of the firsts
        int l1k = t1 ? k1[r][g] : ok1;
        float c2d = t1 ? od2 : d2[r][g];  // winner's own second
        int c2k = t1 ? ok2 : k2[r][g];
        bool t2 = (l1d < c2d) || (l1d == c2d && l1k < c2k);
        d1[r][g] = w1d; k1[r][g] = w1k;
        d2[r][g] = t2 ? l1d : c2d;
        k2[r][g] = t2 ? l1k : c2k;
      }
  }

  if (i0 == 0) {
#pragma unroll
    for (int r = 0; r < 2; ++r)
#pragma unroll
      for (int g = 0; g < 4; ++g)
        sKK[wave * 32 + r * 16 + q * 4 + g] = k1[r][g] | (k2[r][g] << 10);
  }
  __syncthreads();

  // ---- two-pass epilogue: exact fp32 rescore (streaming, no row buffers),
  //      then winner re-read (L2-hot) + coalesced xq store; loss reduce ----
  float lacc = 0.f;
#pragma unroll
  for (int r = 0; r < 2; ++r) {
    int kk = sKK[wave * 32 + r * 16 + i0];
    int ka = kk & 1023, kb = (kk >> 10) & 1023;
    size_t token = (size_t)tok0 + r * 16 + i0;
    float s1 = 0.f, s2 = 0.f;
#pragma unroll
    for (int kf = 0; kf < 4; ++kf) {
      const float* xp = xg + token * 128 + kf * 32 + q * 8;
      float4 xa = *(const float4*)xp, xb = *(const float4*)(xp + 4);
      const float* p1 = cb + (size_t)ka * 128 + kf * 32 + q * 8;
      float4 ua = *(const float4*)p1, ub = *(const float4*)(p1 + 4);
      const float* p2 = cb + (size_t)kb * 128 + kf * 32 + q * 8;
      float4 va = *(const float4*)p2, vb = *(const float4*)(p2 + 4);
      float xv[8] = {xa.x, xa.y, xa.z, xa.w, xb.x, xb.y, xb.z, xb.w};
      float e1[8] = {ua.x, ua.y, ua.z, ua.w, ub.x, ub.y, ub.z, ub.w};
      float e2[8] = {va.x, va.y, va.z, va.w, vb.x, vb.y, vb.z, vb.w};
#pragma unroll
      for (int j = 0; j < 8; ++j) {
        float f1 = xv[j] - e1[j];
        float f2 = xv[j] - e2[j];
        s1 = fmaf(f1, f1, s1);
        s2 = fmaf(f2, f2, s2);
      }
    }
    s1 += __shfl_xor(s1, 16); s1 += __shfl_xor(s1, 32);
    s2 += __shfl_xor(s2, 16); s2 += __shfl_xor(s2, 32);
    bool tk = (s2 < s1) || (s2 == s1 && kb < ka);
    int kw = tk ? kb : ka;
    float dwin = tk ? s2 : s1;
#pragma unroll
    for (int kf = 0; kf < 4; ++kf) {
      const float* pw = cb + (size_t)kw * 128 + kf * 32 + q * 8;
      float4 wa = *(const float4*)pw, wb = *(const float4*)(pw + 4);
      float* op = xq + token * 128 + kf * 32 + q * 8;
      *(float4*)op = wa;
      *(float4*)(op + 4) = wb;
    }
    if (q == 0) lacc += dwin;
  }
#pragma unroll
  for (int off = 1; off < 64; off <<= 1) lacc += __shfl_xor(lacc, off);
  if (lane == 0) atomicAdd(&loss[blockIdx.x], lacc * (1.25f / 16384.f));
}

// ---------------------------------------------------------------------------
extern "C" void kernel_launch(void* const* d_in, const int* in_sizes, int n_in,
                              void* d_out, int out_size, void* d_ws, size_t ws_size,
                              hipStream_t stream) {
  const float* x = (const float*)d_in[0];   // [8,64,128,128] fp32
  const float* cb = (const float*)d_in[1];  // [1024,128] fp32
  float* out = (float*)d_out;
  float* xq = out;
  float* loss = out + (size_t)8 * 64 * 128 * 128;  // 512 floats

  // ws: cbimg 512 KB | cbn 4 KB
  unsigned short* cbimg = (unsigned short*)d_ws;
  float* cbn = (float*)(cbimg + (size_t)1024 * 128 * 2);

  hipMemsetAsync(loss, 0, 512 * sizeof(float), stream);
  vq_convert_cb<<<4, 256, 0, stream>>>(cb, cbimg, cbn);
  vq_main<<<512, 256, 0, stream>>>(x, cb, cbimg, cbn, xq, loss);
}